// Round 9
// baseline (1000.184 us; speedup 1.0000x reference)
//
#include <hip/hip_runtime.h>
#include <hip/hip_bf16.h>
#include <math.h>

#define N_NODES 100000
#define N_EDGES 1600000
#define D 128
#define N_LAYERS 4
#define N_GRAPHS 64
#define N_CLASS 10
#define BN_EPS 1e-5f

#define POOL_ROWS 128
#define LDK 136     // padded LDS row length in bf16 elems (272B = 68 dw = 4 mod 32 banks)

// feature-chunked h layout: h_c[c][node][16], c in 0..7. Per-chunk slice =
// 3.2MB (fits one XCD's 4MB L2). agg pins chunk c to XCD via blockIdx%8.
#define NCH 8
#define CHF 16                      // features per chunk
#define CH_STRIDE ((size_t)N_NODES * CHF)

// bucket CSR build params
#define EB_CHUNK 4096
#define EDGE_BLOCKS ((N_EDGES + EB_CHUNK - 1) / EB_CHUNK)   // 391
#define NPB 512                                             // nodes per bucket (dst >> 9)
#define NB ((N_NODES + NPB - 1) / NPB)                      // 196

typedef __attribute__((ext_vector_type(8))) short bf16x8;   // 8 bf16 = 4 VGPRs
typedef __attribute__((ext_vector_type(4))) float f32x4;    // MFMA acc

__device__ inline float b2f(ushort u) {
    return __builtin_bit_cast(float, (unsigned)u << 16);
}
__device__ inline ushort f2b(float f) {  // RNE bf16
    unsigned u = __builtin_bit_cast(unsigned, f);
    return (ushort)((u + 0x7fffu + ((u >> 16) & 1u)) >> 16);
}

// ---------------- utility: zero a u32 buffer ----------------
__global__ void zero_u32_kernel(unsigned int* __restrict__ p, int n) {
    int i = blockIdx.x * blockDim.x + threadIdx.x;
    if (i < n) p[i] = 0u;
}

// ================= bucketed CSR build (R6: contiguous-write, no line bounce) =============
__global__ void bucket_count_kernel(const int* __restrict__ dst, int* __restrict__ bucketCount) {
    __shared__ int bc[NB];
    int tid = threadIdx.x;
    if (tid < NB) bc[tid] = 0;
    __syncthreads();
    int base = blockIdx.x * EB_CHUNK;
#pragma unroll
    for (int i = 0; i < 16; ++i) {
        int e = base + i * 256 + tid;
        if (e < N_EDGES) atomicAdd(&bc[dst[e] >> 9], 1);
    }
    __syncthreads();
    if (tid < NB && bc[tid]) atomicAdd(&bucketCount[tid], bc[tid]);
}

__global__ void bucket_scan_kernel(const int* __restrict__ bucketCount,
                                   int* __restrict__ bucketBase, int* __restrict__ bucketCursor) {
    __shared__ int lds[256];
    int tid = threadIdx.x;
    int v = (tid < NB) ? bucketCount[tid] : 0;
    lds[tid] = v;
    __syncthreads();
    for (int off = 1; off < 256; off <<= 1) {
        int x = (tid >= off) ? lds[tid - off] : 0;
        __syncthreads();
        lds[tid] += x;
        __syncthreads();
    }
    int excl = lds[tid] - v;
    if (tid < NB) { bucketBase[tid] = excl; bucketCursor[tid] = excl; }
    if (tid == NB - 1) bucketBase[NB] = excl + v;
}

__global__ void bucket_scatter_kernel(const int* __restrict__ src, const int* __restrict__ dst,
                                      int* __restrict__ bucketCursor, int2* __restrict__ bpairs) {
    __shared__ int lcnt[NB];
    int tid = threadIdx.x;
    if (tid < NB) lcnt[tid] = 0;
    __syncthreads();
    int base = blockIdx.x * EB_CHUNK;
    int s[16], d[16];
#pragma unroll
    for (int i = 0; i < 16; ++i) {
        int e = base + i * 256 + tid;
        if (e < N_EDGES) {
            s[i] = src[e]; d[i] = dst[e];
            atomicAdd(&lcnt[d[i] >> 9], 1);
        } else {
            d[i] = -1;
        }
    }
    __syncthreads();
    if (tid < NB) {
        int c = lcnt[tid];
        lcnt[tid] = c ? atomicAdd(&bucketCursor[tid], c) : 0;
    }
    __syncthreads();
#pragma unroll
    for (int i = 0; i < 16; ++i) {
        if (d[i] >= 0) {
            int p = atomicAdd(&lcnt[d[i] >> 9], 1);
            bpairs[p] = make_int2(s[i], d[i]);
        }
    }
}

__launch_bounds__(512)
__global__ void csr_build_kernel(const int2* __restrict__ bpairs, const int* __restrict__ bucketBase,
                                 int* __restrict__ rowptr, int* __restrict__ colidx) {
    __shared__ int cnt[NPB];
    __shared__ int cur[NPB];
    int tid = threadIdx.x;
    int b = blockIdx.x;
    int nb0 = b * NPB;
    int ebase = bucketBase[b];
    int eend = bucketBase[b + 1];
    cnt[tid] = 0;
    __syncthreads();
    for (int e = ebase + tid; e < eend; e += 512)
        atomicAdd(&cnt[bpairs[e].y - nb0], 1);
    __syncthreads();
    int v = cnt[tid];
    for (int off = 1; off < 512; off <<= 1) {
        int x = (tid >= off) ? cnt[tid - off] : 0;
        __syncthreads();
        cnt[tid] += x;
        __syncthreads();
    }
    int excl = cnt[tid] - v;
    int node = nb0 + tid;
    if (node < N_NODES) rowptr[node] = ebase + excl;
    cur[tid] = ebase + excl;
    __syncthreads();
    for (int e = ebase + tid; e < eend; e += 512) {
        int2 pr = bpairs[e];
        int p = atomicAdd(&cur[pr.y - nb0], 1);
        colidx[p] = pr.x;
    }
    if (b == 0 && tid == 0) rowptr[N_NODES] = N_EDGES;
}

// ---------------- standardization ----------------
__global__ void colstats_kernel(const float* __restrict__ x, float* __restrict__ stats) {
    __shared__ float ssum[D];
    __shared__ float ssq[D];
    int tid = threadIdx.x;
    if (tid < D) { ssum[tid] = 0.f; ssq[tid] = 0.f; }
    __syncthreads();
    int f4 = (tid & 31) * 4;
    int rsub = tid >> 5;
    int r0 = blockIdx.x * 128;
    int rend = r0 + 128;
    if (rend > N_NODES) rend = N_NODES;
    float4 ps = make_float4(0.f, 0.f, 0.f, 0.f);
    float4 pq = make_float4(0.f, 0.f, 0.f, 0.f);
    for (int r = r0 + rsub; r < rend; r += 8) {
        float4 v = *(const float4*)&x[(size_t)r * D + f4];
        ps.x += v.x; ps.y += v.y; ps.z += v.z; ps.w += v.w;
        pq.x += v.x * v.x; pq.y += v.y * v.y; pq.z += v.z * v.z; pq.w += v.w * v.w;
    }
    atomicAdd(&ssum[f4 + 0], ps.x); atomicAdd(&ssum[f4 + 1], ps.y);
    atomicAdd(&ssum[f4 + 2], ps.z); atomicAdd(&ssum[f4 + 3], ps.w);
    atomicAdd(&ssq[f4 + 0], pq.x);  atomicAdd(&ssq[f4 + 1], pq.y);
    atomicAdd(&ssq[f4 + 2], pq.z);  atomicAdd(&ssq[f4 + 3], pq.w);
    __syncthreads();
    if (tid < D) {
        atomicAdd(&stats[tid], ssum[tid]);
        atomicAdd(&stats[D + tid], ssq[tid]);
    }
}

// writes bf16 h in chunked layout
__global__ void standardize_kernel(const float* __restrict__ x, const float* __restrict__ stats,
                                   ushort* __restrict__ h) {
    const float invN = 1.f / (float)N_NODES;
    int stride = gridDim.x * blockDim.x;
    const int total = NCH * N_NODES * 4;   // ushort4 units
    for (int idx = blockIdx.x * blockDim.x + threadIdx.x; idx < total; idx += stride) {
        int c = idx / (N_NODES * 4);
        int rem = idx - c * (N_NODES * 4);
        int node = rem >> 2;
        int q = rem & 3;
        int f = c * CHF + q * 4;
        float4 v = *(const float4*)&x[(size_t)node * D + f];
        float o[4];
        float vv[4] = {v.x, v.y, v.z, v.w};
#pragma unroll
        for (int j = 0; j < 4; ++j) {
            float mu = stats[f + j] * invN;
            float sd = sqrtf(stats[D + f + j] * invN - mu * mu);
            o[j] = (vv[j] - mu) / sd;
        }
        *(ushort4*)&h[(size_t)c * CH_STRIDE + (size_t)node * CHF + q * 4] =
            make_ushort4(f2b(o[0]), f2b(o[1]), f2b(o[2]), f2b(o[3]));
    }
}

// ---------------- GIN aggregation, feature-chunked + XCD-affine ----------------
// R7: chunk = blockIdx%8 -> one XCD owns one 3.2MB h-slice (L2-resident).
// 8 lanes x 2 feats per node; 32 nodes per 256-thread block. BN affine +
// relu of previous layer fused per gathered element (layer 0: identity, no relu).
__global__ void agg_kernel(const ushort* __restrict__ h, const int* __restrict__ rowptr,
                           const int* __restrict__ colidx, const float* __restrict__ eps, int l,
                           const float* __restrict__ ab, int relu_flag,
                           ushort* __restrict__ z0) {
    int c = blockIdx.x & 7;
    int ng = blockIdx.x >> 3;
    int tid = threadIdx.x;
    int nsub = tid >> 3;           // 0..31
    int fl = (tid & 7) * 2;        // feature-in-chunk: 0,2,..,14
    int node = ng * 32 + nsub;     // N_NODES % 32 == 0, no guard
    int f = c * CHF + fl;
    const ushort* hp = h + (size_t)c * CH_STRIDE + fl;
    float A0 = ab[f], A1 = ab[f + 1];
    float B0 = ab[D + f], B1 = ab[D + f + 1];
    float lo = relu_flag ? 0.f : -INFINITY;

    uint cs = *(const uint*)&hp[(size_t)node * CHF];
    float se = 1.f + eps[l];
    float a0 = se * fmaxf(fmaf(b2f((ushort)cs), A0, B0), lo);
    float a1 = se * fmaxf(fmaf(b2f((ushort)(cs >> 16)), A1, B1), lo);

    int e = rowptr[node], e1 = rowptr[node + 1];
    for (; e + 2 <= e1; e += 2) {
        int s0 = colidx[e];
        int s1 = colidx[e + 1];
        uint v0 = *(const uint*)&hp[(size_t)s0 * CHF];
        uint v1 = *(const uint*)&hp[(size_t)s1 * CHF];
        a0 += fmaxf(fmaf(b2f((ushort)v0), A0, B0), lo) +
              fmaxf(fmaf(b2f((ushort)v1), A0, B0), lo);
        a1 += fmaxf(fmaf(b2f((ushort)(v0 >> 16)), A1, B1), lo) +
              fmaxf(fmaf(b2f((ushort)(v1 >> 16)), A1, B1), lo);
    }
    if (e < e1) {
        uint v0 = *(const uint*)&hp[(size_t)colidx[e] * CHF];
        a0 += fmaxf(fmaf(b2f((ushort)v0), A0, B0), lo);
        a1 += fmaxf(fmaf(b2f((ushort)(v0 >> 16)), A1, B1), lo);
    }
    *(uint*)&z0[(size_t)c * CH_STRIDE + (size_t)node * CHF + fl] =
        (uint)f2b(a0) | ((uint)f2b(a1) << 16);
}

// ---------------- weight prep: Wt[n][k] bf16 for both MLP weights, all layers ------------
__global__ void prep_wt_kernel(const float* __restrict__ W1, const float* __restrict__ W2,
                               ushort* __restrict__ wt) {
    int idx = blockIdx.x * blockDim.x + threadIdx.x;  // 131072 total
    int w = idx >> 16;
    int rem = idx & 65535;
    int l = rem >> 14;
    int nk = rem & 16383;
    int n = nk >> 7;
    int k = nk & 127;
    const float* W = w ? W2 : W1;
    wt[idx] = f2b(W[((size_t)(l * D + k)) * D + n]);
}

// ---------------- fused MFMA MLP (chunked z0 in / chunked out) ----------------
__launch_bounds__(256, 2)
__global__ void mlp_mfma_kernel(const ushort* __restrict__ z0,
                                const ushort* __restrict__ wt1, const float* __restrict__ b1,
                                const ushort* __restrict__ wt2, const float* __restrict__ b2,
                                ushort* __restrict__ out, float* __restrict__ stats) {
    __shared__ ushort As[128 * LDK];
    __shared__ ushort Bs[128 * LDK];
    __shared__ float Ssum[D];
    __shared__ float Ssq[D];

    int tid = threadIdx.x;
    int lane = tid & 63;
    int wave = tid >> 6;
    int rb = blockIdx.x * 128;
    int lrow = lane & 15;
    int lk = lane >> 4;
    int klane = lk * 8;
    int wr0 = wave * 32;
    int srow = tid >> 1;           // staging row 0..127
    int shalf = (tid & 1) * 8;     // staging half-chunk offset

    if (tid < D) { Ssum[tid] = 0.f; Ssq[tid] = 0.f; }

    // ---- stage A (z0 chunk-major: i = chunk, contiguous 4KB per chunk) and B (wt1) ----
    {
        int sgr = rb + srow;
        bool ok = sgr < N_NODES;
#pragma unroll
        for (int i = 0; i < 8; ++i) {
            bf16x8 v;
#pragma unroll
            for (int e = 0; e < 8; ++e) v[e] = 0;
            if (ok) v = *(const bf16x8*)&z0[(size_t)i * CH_STRIDE + (size_t)sgr * CHF + shalf];
            *(bf16x8*)&As[srow * LDK + i * CHF + shalf] = v;
            int c2 = tid + i * 256;
            *(bf16x8*)&Bs[(c2 >> 4) * LDK + (c2 & 15) * 8] = *(const bf16x8*)&wt1[c2 * 8];
        }
    }
    __syncthreads();

    f32x4 acc[2][8];
#pragma unroll
    for (int a = 0; a < 2; ++a)
#pragma unroll
        for (int b = 0; b < 8; ++b)
#pragma unroll
            for (int r = 0; r < 4; ++r) acc[a][b][r] = 0.f;

#pragma unroll
    for (int ks = 0; ks < 4; ++ks) {
        int k0 = ks * 32 + klane;
        bf16x8 a0 = *(const bf16x8*)&As[(wr0 + lrow) * LDK + k0];
        bf16x8 a1 = *(const bf16x8*)&As[(wr0 + 16 + lrow) * LDK + k0];
#pragma unroll
        for (int ct = 0; ct < 8; ++ct) {
            bf16x8 bb = *(const bf16x8*)&Bs[(ct * 16 + lrow) * LDK + k0];
            acc[0][ct] = __builtin_amdgcn_mfma_f32_16x16x32_bf16(a0, bb, acc[0][ct], 0, 0, 0);
            acc[1][ct] = __builtin_amdgcn_mfma_f32_16x16x32_bf16(a1, bb, acc[1][ct], 0, 0, 0);
        }
    }
    __syncthreads();

#pragma unroll
    for (int rt = 0; rt < 2; ++rt)
#pragma unroll
        for (int ct = 0; ct < 8; ++ct) {
            int col = ct * 16 + lrow;
            float bias = b1[col];
#pragma unroll
            for (int r = 0; r < 4; ++r) {
                int row = wr0 + rt * 16 + lk * 4 + r;
                As[row * LDK + col] = f2b(fmaxf(acc[rt][ct][r] + bias, 0.f));
            }
        }
#pragma unroll
    for (int i = 0; i < 8; ++i) {
        int c2 = tid + i * 256;
        *(bf16x8*)&Bs[(c2 >> 4) * LDK + (c2 & 15) * 8] = *(const bf16x8*)&wt2[c2 * 8];
    }
#pragma unroll
    for (int a = 0; a < 2; ++a)
#pragma unroll
        for (int b = 0; b < 8; ++b)
#pragma unroll
            for (int r = 0; r < 4; ++r) acc[a][b][r] = 0.f;
    __syncthreads();

#pragma unroll
    for (int ks = 0; ks < 4; ++ks) {
        int k0 = ks * 32 + klane;
        bf16x8 a0 = *(const bf16x8*)&As[(wr0 + lrow) * LDK + k0];
        bf16x8 a1 = *(const bf16x8*)&As[(wr0 + 16 + lrow) * LDK + k0];
#pragma unroll
        for (int ct = 0; ct < 8; ++ct) {
            bf16x8 bb = *(const bf16x8*)&Bs[(ct * 16 + lrow) * LDK + k0];
            acc[0][ct] = __builtin_amdgcn_mfma_f32_16x16x32_bf16(a0, bb, acc[0][ct], 0, 0, 0);
            acc[1][ct] = __builtin_amdgcn_mfma_f32_16x16x32_bf16(a1, bb, acc[1][ct], 0, 0, 0);
        }
    }
    __syncthreads();

#pragma unroll
    for (int rt = 0; rt < 2; ++rt)
#pragma unroll
        for (int ct = 0; ct < 8; ++ct) {
            int col = ct * 16 + lrow;
            float bias = b2[col];
            float s = 0.f, sq = 0.f;
#pragma unroll
            for (int r = 0; r < 4; ++r) {
                int row = wr0 + rt * 16 + lk * 4 + r;
                float v = fmaxf(acc[rt][ct][r] + bias, 0.f);
                Bs[row * LDK + col] = f2b(v);
                if (rb + row < N_NODES) { s += v; sq += v * v; }
            }
            atomicAdd(&Ssum[col], s);
            atomicAdd(&Ssq[col], sq);
        }
    __syncthreads();

    // ---- chunked coalesced store + global stats ----
    {
        int sgr = rb + srow;
        if (sgr < N_NODES) {
#pragma unroll
            for (int i = 0; i < 8; ++i)
                *(bf16x8*)&out[(size_t)i * CH_STRIDE + (size_t)sgr * CHF + shalf] =
                    *(const bf16x8*)&Bs[srow * LDK + i * CHF + shalf];
        }
    }
    if (tid < D) {
        atomicAdd(&stats[tid], Ssum[tid]);
        atomicAdd(&stats[D + tid], Ssq[tid]);
    }
}

// ---------------- BN prep: fold stats into per-feature affine A,B ----------------
__global__ void bnprep_kernel(const float* __restrict__ stats, const float* __restrict__ gamma,
                              const float* __restrict__ beta, float* __restrict__ ab) {
    int f = threadIdx.x;
    if (f < D) {
        const float invN = 1.f / (float)N_NODES;
        float mu = stats[f] * invN;
        float var = stats[D + f] * invN - mu * mu;
        float A = gamma[f] * rsqrtf(var + BN_EPS);
        ab[f] = A;
        ab[D + f] = beta[f] - mu * A;
    }
}

__global__ void init_ab_kernel(float* __restrict__ ab) {
    int f = threadIdx.x;
    if (f < D) { ab[f] = 1.f; ab[D + f] = 0.f; }
}

// ---------------- global_add_pool (batch sorted, chunked h) + fused final BN+relu --------
__global__ void pool_kernel(const ushort* __restrict__ h, const int* __restrict__ batch,
                            const float* __restrict__ ab, float* __restrict__ g) {
    int tid = threadIdx.x;
    int f4 = (tid & 31) * 4;
    int c = f4 >> 4;
    int fw = f4 & 15;
    int rsub = tid >> 5;
    int r0 = blockIdx.x * POOL_ROWS;
    int rend = r0 + POOL_ROWS;
    if (rend > N_NODES) rend = N_NODES;
    const ushort* hp = h + (size_t)c * CH_STRIDE + fw;
    float A0 = ab[f4 + 0], A1 = ab[f4 + 1], A2 = ab[f4 + 2], A3 = ab[f4 + 3];
    float B0 = ab[D + f4 + 0], B1 = ab[D + f4 + 1], B2 = ab[D + f4 + 2], B3 = ab[D + f4 + 3];
    float4 acc = make_float4(0.f, 0.f, 0.f, 0.f);
    int cur = -1;
    for (int r = r0 + rsub; r < rend; r += 8) {
        int b = batch[r];
        if (b != cur) {
            if (cur >= 0) {
                atomicAdd(&g[cur * D + f4 + 0], acc.x);
                atomicAdd(&g[cur * D + f4 + 1], acc.y);
                atomicAdd(&g[cur * D + f4 + 2], acc.z);
                atomicAdd(&g[cur * D + f4 + 3], acc.w);
            }
            acc = make_float4(0.f, 0.f, 0.f, 0.f);
            cur = b;
        }
        ushort4 v = *(const ushort4*)&hp[(size_t)r * CHF];
        acc.x += fmaxf(fmaf(b2f(v.x), A0, B0), 0.f);
        acc.y += fmaxf(fmaf(b2f(v.y), A1, B1), 0.f);
        acc.z += fmaxf(fmaf(b2f(v.z), A2, B2), 0.f);
        acc.w += fmaxf(fmaf(b2f(v.w), A3, B3), 0.f);
    }
    if (cur >= 0) {
        atomicAdd(&g[cur * D + f4 + 0], acc.x);
        atomicAdd(&g[cur * D + f4 + 1], acc.y);
        atomicAdd(&g[cur * D + f4 + 2], acc.z);
        atomicAdd(&g[cur * D + f4 + 3], acc.w);
    }
}

// ---------------- MLP head: 64x128 -> 128 -> 64 -> 10 (fp32) ----------------
__launch_bounds__(512)
__global__ void head_kernel(const float* __restrict__ g,
                            const float* __restrict__ fcw1, const float* __restrict__ fcb1,
                            const float* __restrict__ fcw2, const float* __restrict__ fcb2,
                            const float* __restrict__ fcw3, const float* __restrict__ fcb3,
                            float* __restrict__ out) {
    __shared__ float G[64][128];
    __shared__ float T1[64][128];
    __shared__ float T2[64][64];
    int tid = threadIdx.x;
#pragma unroll
    for (int i = 0; i < 4; ++i) {
        int slot = tid + i * 512;
        ((float4*)G)[slot] = ((const float4*)g)[slot];
    }
    __syncthreads();
#pragma unroll 1
    for (int rep = 0; rep < 16; ++rep) {
        int o = tid + rep * 512;
        int r = o >> 7, c = o & 127;
        float acc = fcb1[c];
        for (int k = 0; k < 128; ++k) acc = fmaf(G[r][k], fcw1[k * 128 + c], acc);
        T1[r][c] = fmaxf(acc, 0.f);
    }
    __syncthreads();
#pragma unroll 1
    for (int rep = 0; rep < 8; ++rep) {
        int o = tid + rep * 512;
        int r = o >> 6, c = o & 63;
        float acc = fcb2[c];
        for (int k = 0; k < 128; ++k) acc = fmaf(T1[r][k], fcw2[k * 64 + c], acc);
        T2[r][c] = fmaxf(acc, 0.f);
    }
    __syncthreads();
    for (int o = tid; o < N_GRAPHS * N_CLASS; o += 512) {
        int r = o / 10, c = o % 10;
        float acc = fcb3[c];
        for (int k = 0; k < 64; ++k) acc = fmaf(T2[r][k], fcw3[k * 10 + c], acc);
        out[o] = acc;
    }
}

extern "C" void kernel_launch(void* const* d_in, const int* in_sizes, int n_in,
                              void* d_out, int out_size, void* d_ws, size_t ws_size,
                              hipStream_t stream) {
    const float* x        = (const float*)d_in[0];
    const int* edge_index = (const int*)d_in[1];
    const int* batch      = (const int*)d_in[2];
    const float* W1       = (const float*)d_in[3];
    const float* b1       = (const float*)d_in[4];
    const float* W2       = (const float*)d_in[5];
    const float* b2       = (const float*)d_in[6];
    const float* gamma    = (const float*)d_in[7];
    const float* beta     = (const float*)d_in[8];
    const float* eps      = (const float*)d_in[9];
    const float* fcw1     = (const float*)d_in[10];
    const float* fcb1     = (const float*)d_in[11];
    const float* fcw2     = (const float*)d_in[12];
    const float* fcb2     = (const float*)d_in[13];
    const float* fcw3     = (const float*)d_in[14];
    const float* fcb3     = (const float*)d_in[15];
    float* out = (float*)d_out;

    char* ws = (char*)d_ws;
    size_t off = 0;
    auto alloc = [&](size_t bytes) -> void* {
        void* p = ws + off;
        off = (off + bytes + 255) & ~(size_t)255;
        return p;
    };
    ushort* hbuf   = (ushort*)alloc((size_t)N_NODES * D * 2);           // 25.6 MB bf16 (chunked)
    ushort* z0buf  = (ushort*)alloc((size_t)N_NODES * D * 2);           // 25.6 MB bf16 (chunked)
    ushort* wtbuf  = (ushort*)alloc((size_t)2 * N_LAYERS * D * D * 2);  // 256 KB
    int2* bpairs   = (int2*)alloc((size_t)N_EDGES * 8);                 // 12.8 MB
    int* colidx    = (int*)alloc((size_t)N_EDGES * 4);                  // 6.4 MB
    int* rowptr    = (int*)alloc((size_t)(N_NODES + 1) * 4);
    int* bucketCount  = (int*)alloc((size_t)NB * 4);
    int* bucketBase   = (int*)alloc((size_t)(NB + 1) * 4);
    int* bucketCursor = (int*)alloc((size_t)NB * 4);
    float* stats   = (float*)alloc(4 * D * 4);   // [sum | sumsq | bnA | bnB]
    float* gpool   = (float*)alloc((size_t)N_GRAPHS * D * 4);
    float* ab      = stats + 2 * D;

    const int* srcArr = edge_index;
    const int* dstArr = edge_index + N_EDGES;

    // ---- bucketed CSR build ----
    zero_u32_kernel<<<1, 256, 0, stream>>>((unsigned int*)bucketCount, NB);
    bucket_count_kernel<<<EDGE_BLOCKS, 256, 0, stream>>>(dstArr, bucketCount);
    bucket_scan_kernel<<<1, 256, 0, stream>>>(bucketCount, bucketBase, bucketCursor);
    bucket_scatter_kernel<<<EDGE_BLOCKS, 256, 0, stream>>>(srcArr, dstArr, bucketCursor, bpairs);
    csr_build_kernel<<<NB, 512, 0, stream>>>(bpairs, bucketBase, rowptr, colidx);

    // ---- StandardScaler (h -> bf16, chunked) ----
    zero_u32_kernel<<<1, 256, 0, stream>>>((unsigned int*)stats, 2 * D);
    colstats_kernel<<<(N_NODES + 127) / 128, 256, 0, stream>>>(x, stats);
    standardize_kernel<<<2048, 256, 0, stream>>>(x, stats, hbuf);

    // ---- weight prep + layer-0 identity affine ----
    prep_wt_kernel<<<512, 256, 0, stream>>>(W1, W2, wtbuf);
    init_ab_kernel<<<1, 128, 0, stream>>>(ab);

    // ---- GIN layers (BN+relu fused into consumers; agg chunk = blockIdx%8 -> XCD) ----
    for (int l = 0; l < N_LAYERS; ++l) {
        agg_kernel<<<(N_NODES / 32) * NCH, 256, 0, stream>>>(hbuf, rowptr, colidx, eps, l,
                                                             ab, (l > 0) ? 1 : 0, z0buf);
        zero_u32_kernel<<<1, 256, 0, stream>>>((unsigned int*)stats, 2 * D);
        mlp_mfma_kernel<<<(N_NODES + 127) / 128, 256, 0, stream>>>(
            z0buf, wtbuf + (size_t)l * D * D, b1 + (size_t)l * D,
            wtbuf + (size_t)(N_LAYERS + l) * D * D, b2 + (size_t)l * D, hbuf, stats);
        bnprep_kernel<<<1, 128, 0, stream>>>(stats, gamma + (size_t)l * D,
                                             beta + (size_t)l * D, ab);
    }

    // ---- pool (fused final BN+relu) + head ----
    zero_u32_kernel<<<(N_GRAPHS * D + 255) / 256, 256, 0, stream>>>((unsigned int*)gpool, N_GRAPHS * D);
    pool_kernel<<<(N_NODES + POOL_ROWS - 1) / POOL_ROWS, 256, 0, stream>>>(hbuf, batch, ab, gpool);
    head_kernel<<<1, 512, 0, stream>>>(gpool, fcw1, fcb1, fcw2, fcb2, fcw3, fcb3, out);
}

// Round 10
// 810.374 us; speedup vs baseline: 1.2342x; 1.2342x over previous
//
#include <hip/hip_runtime.h>
#include <hip/hip_bf16.h>
#include <math.h>

#define N_NODES 100000
#define N_EDGES 1600000
#define D 128
#define N_LAYERS 4
#define N_GRAPHS 64
#define N_CLASS 10
#define BN_EPS 1e-5f

#define POOL_ROWS 128
#define LDK 136     // padded LDS row length in bf16 elems (272B = 68 dw = 4 mod 32 banks)

// bucket CSR build params
#define EB_CHUNK 4096
#define EDGE_BLOCKS ((N_EDGES + EB_CHUNK - 1) / EB_CHUNK)   // 391
#define NPB 512                                             // nodes per bucket (dst >> 9)
#define NB ((N_NODES + NPB - 1) / NPB)                      // 196

typedef __attribute__((ext_vector_type(8))) short bf16x8;   // 8 bf16 = 4 VGPRs
typedef __attribute__((ext_vector_type(4))) float f32x4;    // MFMA acc

__device__ inline float b2f(ushort u) {
    return __builtin_bit_cast(float, (unsigned)u << 16);
}
__device__ inline ushort f2b(float f) {  // RNE bf16
    unsigned u = __builtin_bit_cast(unsigned, f);
    return (ushort)((u + 0x7fffu + ((u >> 16) & 1u)) >> 16);
}

// ---------------- one-shot prep: zero stats slabs/gpool/bucketCount, ab=identity ---------
// statsAll layout: [l0 sum|sq][l1][l2][l3][scaler sum|sq] = 10*D floats; ab follows.
__global__ void prep_all_kernel(float* __restrict__ statsAll, float* __restrict__ ab,
                                float* __restrict__ gpool, int* __restrict__ bucketCount) {
    int t = threadIdx.x;  // 1024
    for (int i = t; i < 10 * D; i += 1024) statsAll[i] = 0.f;
    if (t < D) { ab[t] = 1.f; ab[D + t] = 0.f; }
    for (int i = t; i < N_GRAPHS * D; i += 1024) gpool[i] = 0.f;
    for (int i = t; i < NB; i += 1024) bucketCount[i] = 0;
}

// ================= bucketed CSR build (R6: contiguous-write, no line bounce) =============
__global__ void bucket_count_kernel(const int* __restrict__ dst, int* __restrict__ bucketCount) {
    __shared__ int bc[NB];
    int tid = threadIdx.x;
    if (tid < NB) bc[tid] = 0;
    __syncthreads();
    int base = blockIdx.x * EB_CHUNK;
#pragma unroll
    for (int i = 0; i < 16; ++i) {
        int e = base + i * 256 + tid;
        if (e < N_EDGES) atomicAdd(&bc[dst[e] >> 9], 1);
    }
    __syncthreads();
    if (tid < NB && bc[tid]) atomicAdd(&bucketCount[tid], bc[tid]);
}

__global__ void bucket_scan_kernel(const int* __restrict__ bucketCount,
                                   int* __restrict__ bucketBase, int* __restrict__ bucketCursor) {
    __shared__ int lds[256];
    int tid = threadIdx.x;
    int v = (tid < NB) ? bucketCount[tid] : 0;
    lds[tid] = v;
    __syncthreads();
    for (int off = 1; off < 256; off <<= 1) {
        int x = (tid >= off) ? lds[tid - off] : 0;
        __syncthreads();
        lds[tid] += x;
        __syncthreads();
    }
    int excl = lds[tid] - v;
    if (tid < NB) { bucketBase[tid] = excl; bucketCursor[tid] = excl; }
    if (tid == NB - 1) bucketBase[NB] = excl + v;
}

__global__ void bucket_scatter_kernel(const int* __restrict__ src, const int* __restrict__ dst,
                                      int* __restrict__ bucketCursor, int2* __restrict__ bpairs) {
    __shared__ int lcnt[NB];
    int tid = threadIdx.x;
    if (tid < NB) lcnt[tid] = 0;
    __syncthreads();
    int base = blockIdx.x * EB_CHUNK;
    int s[16], d[16];
#pragma unroll
    for (int i = 0; i < 16; ++i) {
        int e = base + i * 256 + tid;
        if (e < N_EDGES) {
            s[i] = src[e]; d[i] = dst[e];
            atomicAdd(&lcnt[d[i] >> 9], 1);
        } else {
            d[i] = -1;
        }
    }
    __syncthreads();
    if (tid < NB) {
        int c = lcnt[tid];
        lcnt[tid] = c ? atomicAdd(&bucketCursor[tid], c) : 0;
    }
    __syncthreads();
#pragma unroll
    for (int i = 0; i < 16; ++i) {
        if (d[i] >= 0) {
            int p = atomicAdd(&lcnt[d[i] >> 9], 1);
            bpairs[p] = make_int2(s[i], d[i]);
        }
    }
}

__launch_bounds__(512)
__global__ void csr_build_kernel(const int2* __restrict__ bpairs, const int* __restrict__ bucketBase,
                                 int* __restrict__ rowptr, int* __restrict__ colidx) {
    __shared__ int cnt[NPB];
    __shared__ int cur[NPB];
    int tid = threadIdx.x;
    int b = blockIdx.x;
    int nb0 = b * NPB;
    int ebase = bucketBase[b];
    int eend = bucketBase[b + 1];
    cnt[tid] = 0;
    __syncthreads();
    for (int e = ebase + tid; e < eend; e += 512)
        atomicAdd(&cnt[bpairs[e].y - nb0], 1);
    __syncthreads();
    int v = cnt[tid];
    for (int off = 1; off < 512; off <<= 1) {
        int x = (tid >= off) ? cnt[tid - off] : 0;
        __syncthreads();
        cnt[tid] += x;
        __syncthreads();
    }
    int excl = cnt[tid] - v;
    int node = nb0 + tid;
    if (node < N_NODES) rowptr[node] = ebase + excl;
    cur[tid] = ebase + excl;
    __syncthreads();
    for (int e = ebase + tid; e < eend; e += 512) {
        int2 pr = bpairs[e];
        int p = atomicAdd(&cur[pr.y - nb0], 1);
        colidx[p] = pr.x;
    }
    if (b == 0 && tid == 0) rowptr[N_NODES] = N_EDGES;
}

// ---------------- standardization ----------------
__global__ void colstats_kernel(const float* __restrict__ x, float* __restrict__ stats) {
    __shared__ float ssum[D];
    __shared__ float ssq[D];
    int tid = threadIdx.x;
    if (tid < D) { ssum[tid] = 0.f; ssq[tid] = 0.f; }
    __syncthreads();
    int f4 = (tid & 31) * 4;
    int rsub = tid >> 5;
    int r0 = blockIdx.x * 128;
    int rend = r0 + 128;
    if (rend > N_NODES) rend = N_NODES;
    float4 ps = make_float4(0.f, 0.f, 0.f, 0.f);
    float4 pq = make_float4(0.f, 0.f, 0.f, 0.f);
    for (int r = r0 + rsub; r < rend; r += 8) {
        float4 v = *(const float4*)&x[(size_t)r * D + f4];
        ps.x += v.x; ps.y += v.y; ps.z += v.z; ps.w += v.w;
        pq.x += v.x * v.x; pq.y += v.y * v.y; pq.z += v.z * v.z; pq.w += v.w * v.w;
    }
    atomicAdd(&ssum[f4 + 0], ps.x); atomicAdd(&ssum[f4 + 1], ps.y);
    atomicAdd(&ssum[f4 + 2], ps.z); atomicAdd(&ssum[f4 + 3], ps.w);
    atomicAdd(&ssq[f4 + 0], pq.x);  atomicAdd(&ssq[f4 + 1], pq.y);
    atomicAdd(&ssq[f4 + 2], pq.z);  atomicAdd(&ssq[f4 + 3], pq.w);
    __syncthreads();
    if (tid < D) {
        atomicAdd(&stats[tid], ssum[tid]);
        atomicAdd(&stats[D + tid], ssq[tid]);
    }
}

// writes bf16 h (row-major [node][D] — R9: reverted from chunked layout)
__global__ void standardize_kernel(const float* __restrict__ x, const float* __restrict__ stats,
                                   ushort* __restrict__ h) {
    const float invN = 1.f / (float)N_NODES;
    int stride = gridDim.x * blockDim.x;
    const int total = N_NODES * (D / 4);
    for (int idx = blockIdx.x * blockDim.x + threadIdx.x; idx < total; idx += stride) {
        int f = (idx & 31) * 4;
        float4 v = ((const float4*)x)[idx];
        float o[4];
        float vv[4] = {v.x, v.y, v.z, v.w};
#pragma unroll
        for (int j = 0; j < 4; ++j) {
            float mu = stats[f + j] * invN;
            float sd = sqrtf(stats[D + f + j] * invN - mu * mu);
            o[j] = (vv[j] - mu) / sd;
        }
        ((ushort4*)h)[idx] = make_ushort4(f2b(o[0]), f2b(o[1]), f2b(o[2]), f2b(o[3]));
    }
}

// ---------------- GIN aggregation (row-major h, fused BN affine + relu) ----------------
// R9: reverted to R6 form (256B/edge fully-utilized gathers; chunked 32B
// gathers were issue-bound: FETCH 54MB but 112us vs 72us). Added 4-edge
// unroll for more loads in flight (latency-bound component test).
__global__ void agg_kernel(const ushort* __restrict__ h, const int* __restrict__ rowptr,
                           const int* __restrict__ colidx, const float* __restrict__ eps, int l,
                           const float* __restrict__ ab, int relu_flag,
                           ushort* __restrict__ z0) {
    int node = blockIdx.x * 8 + (threadIdx.x >> 5);
    int f4 = (threadIdx.x & 31) * 4;
    const ushort* hp = h + f4;
    float A0 = ab[f4 + 0], A1 = ab[f4 + 1], A2 = ab[f4 + 2], A3 = ab[f4 + 3];
    float B0 = ab[D + f4 + 0], B1 = ab[D + f4 + 1], B2 = ab[D + f4 + 2], B3 = ab[D + f4 + 3];
    float lo = relu_flag ? 0.f : -INFINITY;
    auto R0 = [&](ushort u) { return fmaxf(fmaf(b2f(u), A0, B0), lo); };
    auto R1 = [&](ushort u) { return fmaxf(fmaf(b2f(u), A1, B1), lo); };
    auto R2 = [&](ushort u) { return fmaxf(fmaf(b2f(u), A2, B2), lo); };
    auto R3 = [&](ushort u) { return fmaxf(fmaf(b2f(u), A3, B3), lo); };

    ushort4 c = *(const ushort4*)&hp[(size_t)node * D];
    float se = 1.f + eps[l];
    float ax = se * R0(c.x), ay = se * R1(c.y), az = se * R2(c.z), aw = se * R3(c.w);

    int e = rowptr[node], e1 = rowptr[node + 1];
    for (; e + 4 <= e1; e += 4) {
        int s0 = colidx[e], s1 = colidx[e + 1], s2 = colidx[e + 2], s3 = colidx[e + 3];
        ushort4 v0 = *(const ushort4*)&hp[(size_t)s0 * D];
        ushort4 v1 = *(const ushort4*)&hp[(size_t)s1 * D];
        ushort4 v2 = *(const ushort4*)&hp[(size_t)s2 * D];
        ushort4 v3 = *(const ushort4*)&hp[(size_t)s3 * D];
        ax += (R0(v0.x) + R0(v1.x)) + (R0(v2.x) + R0(v3.x));
        ay += (R1(v0.y) + R1(v1.y)) + (R1(v2.y) + R1(v3.y));
        az += (R2(v0.z) + R2(v1.z)) + (R2(v2.z) + R2(v3.z));
        aw += (R3(v0.w) + R3(v1.w)) + (R3(v2.w) + R3(v3.w));
    }
    for (; e < e1; ++e) {
        ushort4 v0 = *(const ushort4*)&hp[(size_t)colidx[e] * D];
        ax += R0(v0.x); ay += R1(v0.y); az += R2(v0.z); aw += R3(v0.w);
    }
    *(ushort4*)&z0[(size_t)node * D + f4] = make_ushort4(f2b(ax), f2b(ay), f2b(az), f2b(aw));
}

// ---------------- weight prep: Wt[n][k] bf16 for both MLP weights, all layers ------------
__global__ void prep_wt_kernel(const float* __restrict__ W1, const float* __restrict__ W2,
                               ushort* __restrict__ wt) {
    int idx = blockIdx.x * blockDim.x + threadIdx.x;  // 131072 total
    int w = idx >> 16;
    int rem = idx & 65535;
    int l = rem >> 14;
    int nk = rem & 16383;
    int n = nk >> 7;
    int k = nk & 127;
    const float* W = w ? W2 : W1;
    wt[idx] = f2b(W[((size_t)(l * D + k)) * D + n]);
}

// ---------------- fused MFMA MLP: z2 = relu(relu(z0@W1+b1)@W2+b2), + BN stats ------------
__launch_bounds__(256, 2)
__global__ void mlp_mfma_kernel(const ushort* __restrict__ z0,
                                const ushort* __restrict__ wt1, const float* __restrict__ b1,
                                const ushort* __restrict__ wt2, const float* __restrict__ b2,
                                ushort* __restrict__ out, float* __restrict__ stats) {
    __shared__ ushort As[128 * LDK];
    __shared__ ushort Bs[128 * LDK];
    __shared__ float Ssum[D];
    __shared__ float Ssq[D];

    int tid = threadIdx.x;
    int lane = tid & 63;
    int wave = tid >> 6;
    int rb = blockIdx.x * 128;
    int lrow = lane & 15;
    int lk = lane >> 4;
    int klane = lk * 8;
    int wr0 = wave * 32;

    if (tid < D) { Ssum[tid] = 0.f; Ssq[tid] = 0.f; }

#pragma unroll
    for (int i = 0; i < 8; ++i) {
        int c2 = tid + i * 256;
        int row = c2 >> 4;
        int cc = (c2 & 15) * 8;
        int gr = rb + row;
        bf16x8 v;
#pragma unroll
        for (int e = 0; e < 8; ++e) v[e] = 0;
        if (gr < N_NODES) v = *(const bf16x8*)&z0[(size_t)gr * D + cc];
        *(bf16x8*)&As[row * LDK + cc] = v;
        *(bf16x8*)&Bs[row * LDK + cc] = *(const bf16x8*)&wt1[c2 * 8];
    }
    __syncthreads();

    f32x4 acc[2][8];
#pragma unroll
    for (int a = 0; a < 2; ++a)
#pragma unroll
        for (int b = 0; b < 8; ++b)
#pragma unroll
            for (int r = 0; r < 4; ++r) acc[a][b][r] = 0.f;

#pragma unroll
    for (int ks = 0; ks < 4; ++ks) {
        int k0 = ks * 32 + klane;
        bf16x8 a0 = *(const bf16x8*)&As[(wr0 + lrow) * LDK + k0];
        bf16x8 a1 = *(const bf16x8*)&As[(wr0 + 16 + lrow) * LDK + k0];
#pragma unroll
        for (int ct = 0; ct < 8; ++ct) {
            bf16x8 bb = *(const bf16x8*)&Bs[(ct * 16 + lrow) * LDK + k0];
            acc[0][ct] = __builtin_amdgcn_mfma_f32_16x16x32_bf16(a0, bb, acc[0][ct], 0, 0, 0);
            acc[1][ct] = __builtin_amdgcn_mfma_f32_16x16x32_bf16(a1, bb, acc[1][ct], 0, 0, 0);
        }
    }
    __syncthreads();

#pragma unroll
    for (int rt = 0; rt < 2; ++rt)
#pragma unroll
        for (int ct = 0; ct < 8; ++ct) {
            int col = ct * 16 + lrow;
            float bias = b1[col];
#pragma unroll
            for (int r = 0; r < 4; ++r) {
                int row = wr0 + rt * 16 + lk * 4 + r;
                As[row * LDK + col] = f2b(fmaxf(acc[rt][ct][r] + bias, 0.f));
            }
        }
#pragma unroll
    for (int i = 0; i < 8; ++i) {
        int c2 = tid + i * 256;
        *(bf16x8*)&Bs[(c2 >> 4) * LDK + (c2 & 15) * 8] = *(const bf16x8*)&wt2[c2 * 8];
    }
#pragma unroll
    for (int a = 0; a < 2; ++a)
#pragma unroll
        for (int b = 0; b < 8; ++b)
#pragma unroll
            for (int r = 0; r < 4; ++r) acc[a][b][r] = 0.f;
    __syncthreads();

#pragma unroll
    for (int ks = 0; ks < 4; ++ks) {
        int k0 = ks * 32 + klane;
        bf16x8 a0 = *(const bf16x8*)&As[(wr0 + lrow) * LDK + k0];
        bf16x8 a1 = *(const bf16x8*)&As[(wr0 + 16 + lrow) * LDK + k0];
#pragma unroll
        for (int ct = 0; ct < 8; ++ct) {
            bf16x8 bb = *(const bf16x8*)&Bs[(ct * 16 + lrow) * LDK + k0];
            acc[0][ct] = __builtin_amdgcn_mfma_f32_16x16x32_bf16(a0, bb, acc[0][ct], 0, 0, 0);
            acc[1][ct] = __builtin_amdgcn_mfma_f32_16x16x32_bf16(a1, bb, acc[1][ct], 0, 0, 0);
        }
    }
    __syncthreads();

#pragma unroll
    for (int rt = 0; rt < 2; ++rt)
#pragma unroll
        for (int ct = 0; ct < 8; ++ct) {
            int col = ct * 16 + lrow;
            float bias = b2[col];
            float s = 0.f, sq = 0.f;
#pragma unroll
            for (int r = 0; r < 4; ++r) {
                int row = wr0 + rt * 16 + lk * 4 + r;
                float v = fmaxf(acc[rt][ct][r] + bias, 0.f);
                Bs[row * LDK + col] = f2b(v);
                if (rb + row < N_NODES) { s += v; sq += v * v; }
            }
            atomicAdd(&Ssum[col], s);
            atomicAdd(&Ssq[col], sq);
        }
    __syncthreads();

#pragma unroll
    for (int i = 0; i < 8; ++i) {
        int c2 = tid + i * 256;
        int row = c2 >> 4;
        int cc = (c2 & 15) * 8;
        int gr = rb + row;
        if (gr < N_NODES)
            *(bf16x8*)&out[(size_t)gr * D + cc] = *(const bf16x8*)&Bs[row * LDK + cc];
    }
    if (tid < D) {
        atomicAdd(&stats[tid], Ssum[tid]);
        atomicAdd(&stats[D + tid], Ssq[tid]);
    }
}

// ---------------- BN prep: fold stats into per-feature affine A,B ----------------
__global__ void bnprep_kernel(const float* __restrict__ stats, const float* __restrict__ gamma,
                              const float* __restrict__ beta, float* __restrict__ ab) {
    int f = threadIdx.x;
    if (f < D) {
        const float invN = 1.f / (float)N_NODES;
        float mu = stats[f] * invN;
        float var = stats[D + f] * invN - mu * mu;
        float A = gamma[f] * rsqrtf(var + BN_EPS);
        ab[f] = A;
        ab[D + f] = beta[f] - mu * A;
    }
}

// ---------------- global_add_pool (batch sorted, row-major h) + fused final BN+relu ------
__global__ void pool_kernel(const ushort* __restrict__ h, const int* __restrict__ batch,
                            const float* __restrict__ ab, float* __restrict__ g) {
    int tid = threadIdx.x;
    int f4 = (tid & 31) * 4;
    int rsub = tid >> 5;
    int r0 = blockIdx.x * POOL_ROWS;
    int rend = r0 + POOL_ROWS;
    if (rend > N_NODES) rend = N_NODES;
    float A0 = ab[f4 + 0], A1 = ab[f4 + 1], A2 = ab[f4 + 2], A3 = ab[f4 + 3];
    float B0 = ab[D + f4 + 0], B1 = ab[D + f4 + 1], B2 = ab[D + f4 + 2], B3 = ab[D + f4 + 3];
    float4 acc = make_float4(0.f, 0.f, 0.f, 0.f);
    int cur = -1;
    for (int r = r0 + rsub; r < rend; r += 8) {
        int b = batch[r];
        if (b != cur) {
            if (cur >= 0) {
                atomicAdd(&g[cur * D + f4 + 0], acc.x);
                atomicAdd(&g[cur * D + f4 + 1], acc.y);
                atomicAdd(&g[cur * D + f4 + 2], acc.z);
                atomicAdd(&g[cur * D + f4 + 3], acc.w);
            }
            acc = make_float4(0.f, 0.f, 0.f, 0.f);
            cur = b;
        }
        ushort4 v = *(const ushort4*)&h[(size_t)r * D + f4];
        acc.x += fmaxf(fmaf(b2f(v.x), A0, B0), 0.f);
        acc.y += fmaxf(fmaf(b2f(v.y), A1, B1), 0.f);
        acc.z += fmaxf(fmaf(b2f(v.z), A2, B2), 0.f);
        acc.w += fmaxf(fmaf(b2f(v.w), A3, B3), 0.f);
    }
    if (cur >= 0) {
        atomicAdd(&g[cur * D + f4 + 0], acc.x);
        atomicAdd(&g[cur * D + f4 + 1], acc.y);
        atomicAdd(&g[cur * D + f4 + 2], acc.z);
        atomicAdd(&g[cur * D + f4 + 3], acc.w);
    }
}

// ---------------- MLP head: 64x128 -> 128 -> 64 -> 10 (fp32) ----------------
__launch_bounds__(512)
__global__ void head_kernel(const float* __restrict__ g,
                            const float* __restrict__ fcw1, const float* __restrict__ fcb1,
                            const float* __restrict__ fcw2, const float* __restrict__ fcb2,
                            const float* __restrict__ fcw3, const float* __restrict__ fcb3,
                            float* __restrict__ out) {
    __shared__ float G[64][128];
    __shared__ float T1[64][128];
    __shared__ float T2[64][64];
    int tid = threadIdx.x;
#pragma unroll
    for (int i = 0; i < 4; ++i) {
        int slot = tid + i * 512;
        ((float4*)G)[slot] = ((const float4*)g)[slot];
    }
    __syncthreads();
#pragma unroll 1
    for (int rep = 0; rep < 16; ++rep) {
        int o = tid + rep * 512;
        int r = o >> 7, c = o & 127;
        float acc = fcb1[c];
        for (int k = 0; k < 128; ++k) acc = fmaf(G[r][k], fcw1[k * 128 + c], acc);
        T1[r][c] = fmaxf(acc, 0.f);
    }
    __syncthreads();
#pragma unroll 1
    for (int rep = 0; rep < 8; ++rep) {
        int o = tid + rep * 512;
        int r = o >> 6, c = o & 63;
        float acc = fcb2[c];
        for (int k = 0; k < 128; ++k) acc = fmaf(T1[r][k], fcw2[k * 64 + c], acc);
        T2[r][c] = fmaxf(acc, 0.f);
    }
    __syncthreads();
    for (int o = tid; o < N_GRAPHS * N_CLASS; o += 512) {
        int r = o / 10, c = o % 10;
        float acc = fcb3[c];
        for (int k = 0; k < 64; ++k) acc = fmaf(T2[r][k], fcw3[k * 10 + c], acc);
        out[o] = acc;
    }
}

extern "C" void kernel_launch(void* const* d_in, const int* in_sizes, int n_in,
                              void* d_out, int out_size, void* d_ws, size_t ws_size,
                              hipStream_t stream) {
    const float* x        = (const float*)d_in[0];
    const int* edge_index = (const int*)d_in[1];
    const int* batch      = (const int*)d_in[2];
    const float* W1       = (const float*)d_in[3];
    const float* b1       = (const float*)d_in[4];
    const float* W2       = (const float*)d_in[5];
    const float* b2       = (const float*)d_in[6];
    const float* gamma    = (const float*)d_in[7];
    const float* beta     = (const float*)d_in[8];
    const float* eps      = (const float*)d_in[9];
    const float* fcw1     = (const float*)d_in[10];
    const float* fcb1     = (const float*)d_in[11];
    const float* fcw2     = (const float*)d_in[12];
    const float* fcb2     = (const float*)d_in[13];
    const float* fcw3     = (const float*)d_in[14];
    const float* fcb3     = (const float*)d_in[15];
    float* out = (float*)d_out;

    char* ws = (char*)d_ws;
    size_t off = 0;
    auto alloc = [&](size_t bytes) -> void* {
        void* p = ws + off;
        off = (off + bytes + 255) & ~(size_t)255;
        return p;
    };
    ushort* hbuf   = (ushort*)alloc((size_t)N_NODES * D * 2);           // 25.6 MB bf16
    ushort* z0buf  = (ushort*)alloc((size_t)N_NODES * D * 2);           // 25.6 MB bf16
    ushort* wtbuf  = (ushort*)alloc((size_t)2 * N_LAYERS * D * D * 2);  // 256 KB
    int2* bpairs   = (int2*)alloc((size_t)N_EDGES * 8);                 // 12.8 MB
    int* colidx    = (int*)alloc((size_t)N_EDGES * 4);                  // 6.4 MB
    int* rowptr    = (int*)alloc((size_t)(N_NODES + 1) * 4);
    int* bucketCount  = (int*)alloc((size_t)NB * 4);
    int* bucketBase   = (int*)alloc((size_t)(NB + 1) * 4);
    int* bucketCursor = (int*)alloc((size_t)NB * 4);
    float* statsAll = (float*)alloc(12 * D * 4);  // [l0 sum|sq][l1][l2][l3][scaler][abA|abB]
    float* gpool   = (float*)alloc((size_t)N_GRAPHS * D * 4);
    float* scalerStats = statsAll + 8 * D;
    float* ab          = statsAll + 10 * D;

    const int* srcArr = edge_index;
    const int* dstArr = edge_index + N_EDGES;

    // ---- one-shot prep (stats slabs, ab identity, gpool, bucketCount) ----
    prep_all_kernel<<<1, 1024, 0, stream>>>(statsAll, ab, gpool, bucketCount);

    // ---- bucketed CSR build ----
    bucket_count_kernel<<<EDGE_BLOCKS, 256, 0, stream>>>(dstArr, bucketCount);
    bucket_scan_kernel<<<1, 256, 0, stream>>>(bucketCount, bucketBase, bucketCursor);
    bucket_scatter_kernel<<<EDGE_BLOCKS, 256, 0, stream>>>(srcArr, dstArr, bucketCursor, bpairs);
    csr_build_kernel<<<NB, 512, 0, stream>>>(bpairs, bucketBase, rowptr, colidx);

    // ---- StandardScaler (h -> bf16) ----
    colstats_kernel<<<(N_NODES + 127) / 128, 256, 0, stream>>>(x, scalerStats);
    standardize_kernel<<<2048, 256, 0, stream>>>(x, scalerStats, hbuf);

    // ---- weight prep ----
    prep_wt_kernel<<<512, 256, 0, stream>>>(W1, W2, wtbuf);

    // ---- GIN layers (BN+relu of layer l fused into consumers of h_l) ----
    for (int l = 0; l < N_LAYERS; ++l) {
        float* lstats = statsAll + (size_t)l * 2 * D;
        agg_kernel<<<N_NODES / 8, 256, 0, stream>>>(hbuf, rowptr, colidx, eps, l,
                                                    ab, (l > 0) ? 1 : 0, z0buf);
        mlp_mfma_kernel<<<(N_NODES + 127) / 128, 256, 0, stream>>>(
            z0buf, wtbuf + (size_t)l * D * D, b1 + (size_t)l * D,
            wtbuf + (size_t)(N_LAYERS + l) * D * D, b2 + (size_t)l * D, hbuf, lstats);
        bnprep_kernel<<<1, 128, 0, stream>>>(lstats, gamma + (size_t)l * D,
                                             beta + (size_t)l * D, ab);
    }

    // ---- pool (fused final BN+relu) + head ----
    pool_kernel<<<(N_NODES + POOL_ROWS - 1) / POOL_ROWS, 256, 0, stream>>>(hbuf, batch, ab, gpool);
    head_kernel<<<1, 512, 0, stream>>>(gpool, fcw1, fcb1, fcw2, fcb2, fcw3, fcb3, out);
}

// Round 11
// 788.341 us; speedup vs baseline: 1.2687x; 1.0279x over previous
//
#include <hip/hip_runtime.h>
#include <hip/hip_bf16.h>
#include <math.h>

#define N_NODES 100000
#define N_EDGES 1600000
#define D 128
#define N_LAYERS 4
#define N_GRAPHS 64
#define N_CLASS 10
#define BN_EPS 1e-5f

#define POOL_ROWS 128
#define LDK 136     // padded LDS row length in bf16 elems (272B = 68 dw = 4 mod 32 banks)

// bucket CSR build params
#define EB_CHUNK 4096
#define EDGE_BLOCKS ((N_EDGES + EB_CHUNK - 1) / EB_CHUNK)   // 391
#define NPB 512                                             // nodes per bucket (dst >> 9)
#define NB ((N_NODES + NPB - 1) / NPB)                      // 196

typedef __attribute__((ext_vector_type(8))) short bf16x8;   // 8 bf16 = 4 VGPRs
typedef __attribute__((ext_vector_type(4))) float f32x4;    // MFMA acc

__device__ inline float b2f(ushort u) {
    return __builtin_bit_cast(float, (unsigned)u << 16);
}
__device__ inline ushort f2b(float f) {  // RNE bf16
    unsigned u = __builtin_bit_cast(unsigned, f);
    return (ushort)((u + 0x7fffu + ((u >> 16) & 1u)) >> 16);
}

// ---------------- one-shot prep: zero stats slabs/gpool/bucketCount, ab=identity ---------
// statsAll layout: [l0 sum|sq][l1][l2][l3][scaler sum|sq] = 10*D floats; ab follows.
__global__ void prep_all_kernel(float* __restrict__ statsAll, float* __restrict__ ab,
                                float* __restrict__ gpool, int* __restrict__ bucketCount) {
    int t = threadIdx.x;  // 1024
    for (int i = t; i < 10 * D; i += 1024) statsAll[i] = 0.f;
    if (t < D) { ab[t] = 1.f; ab[D + t] = 0.f; }
    for (int i = t; i < N_GRAPHS * D; i += 1024) gpool[i] = 0.f;
    for (int i = t; i < NB; i += 1024) bucketCount[i] = 0;
}

// ================= bucketed CSR build (R6: contiguous-write, no line bounce) =============
__global__ void bucket_count_kernel(const int* __restrict__ dst, int* __restrict__ bucketCount) {
    __shared__ int bc[NB];
    int tid = threadIdx.x;
    if (tid < NB) bc[tid] = 0;
    __syncthreads();
    int base = blockIdx.x * EB_CHUNK;
#pragma unroll
    for (int i = 0; i < 16; ++i) {
        int e = base + i * 256 + tid;
        if (e < N_EDGES) atomicAdd(&bc[dst[e] >> 9], 1);
    }
    __syncthreads();
    if (tid < NB && bc[tid]) atomicAdd(&bucketCount[tid], bc[tid]);
}

__global__ void bucket_scan_kernel(const int* __restrict__ bucketCount,
                                   int* __restrict__ bucketBase, int* __restrict__ bucketCursor) {
    __shared__ int lds[256];
    int tid = threadIdx.x;
    int v = (tid < NB) ? bucketCount[tid] : 0;
    lds[tid] = v;
    __syncthreads();
    for (int off = 1; off < 256; off <<= 1) {
        int x = (tid >= off) ? lds[tid - off] : 0;
        __syncthreads();
        lds[tid] += x;
        __syncthreads();
    }
    int excl = lds[tid] - v;
    if (tid < NB) { bucketBase[tid] = excl; bucketCursor[tid] = excl; }
    if (tid == NB - 1) bucketBase[NB] = excl + v;
}

__global__ void bucket_scatter_kernel(const int* __restrict__ src, const int* __restrict__ dst,
                                      int* __restrict__ bucketCursor, int2* __restrict__ bpairs) {
    __shared__ int lcnt[NB];
    int tid = threadIdx.x;
    if (tid < NB) lcnt[tid] = 0;
    __syncthreads();
    int base = blockIdx.x * EB_CHUNK;
    int s[16], d[16];
#pragma unroll
    for (int i = 0; i < 16; ++i) {
        int e = base + i * 256 + tid;
        if (e < N_EDGES) {
            s[i] = src[e]; d[i] = dst[e];
            atomicAdd(&lcnt[d[i] >> 9], 1);
        } else {
            d[i] = -1;
        }
    }
    __syncthreads();
    if (tid < NB) {
        int c = lcnt[tid];
        lcnt[tid] = c ? atomicAdd(&bucketCursor[tid], c) : 0;
    }
    __syncthreads();
#pragma unroll
    for (int i = 0; i < 16; ++i) {
        if (d[i] >= 0) {
            int p = atomicAdd(&lcnt[d[i] >> 9], 1);
            bpairs[p] = make_int2(s[i], d[i]);
        }
    }
}

__launch_bounds__(512)
__global__ void csr_build_kernel(const int2* __restrict__ bpairs, const int* __restrict__ bucketBase,
                                 int* __restrict__ rowptr, int* __restrict__ colidx) {
    __shared__ int cnt[NPB];
    __shared__ int cur[NPB];
    int tid = threadIdx.x;
    int b = blockIdx.x;
    int nb0 = b * NPB;
    int ebase = bucketBase[b];
    int eend = bucketBase[b + 1];
    cnt[tid] = 0;
    __syncthreads();
    for (int e = ebase + tid; e < eend; e += 512)
        atomicAdd(&cnt[bpairs[e].y - nb0], 1);
    __syncthreads();
    int v = cnt[tid];
    for (int off = 1; off < 512; off <<= 1) {
        int x = (tid >= off) ? cnt[tid - off] : 0;
        __syncthreads();
        cnt[tid] += x;
        __syncthreads();
    }
    int excl = cnt[tid] - v;
    int node = nb0 + tid;
    if (node < N_NODES) rowptr[node] = ebase + excl;
    cur[tid] = ebase + excl;
    __syncthreads();
    for (int e = ebase + tid; e < eend; e += 512) {
        int2 pr = bpairs[e];
        int p = atomicAdd(&cur[pr.y - nb0], 1);
        colidx[p] = pr.x;
    }
    if (b == 0 && tid == 0) rowptr[N_NODES] = N_EDGES;
}

// ---------------- standardization ----------------
__global__ void colstats_kernel(const float* __restrict__ x, float* __restrict__ stats) {
    __shared__ float ssum[D];
    __shared__ float ssq[D];
    int tid = threadIdx.x;
    if (tid < D) { ssum[tid] = 0.f; ssq[tid] = 0.f; }
    __syncthreads();
    int f4 = (tid & 31) * 4;
    int rsub = tid >> 5;
    int r0 = blockIdx.x * 128;
    int rend = r0 + 128;
    if (rend > N_NODES) rend = N_NODES;
    float4 ps = make_float4(0.f, 0.f, 0.f, 0.f);
    float4 pq = make_float4(0.f, 0.f, 0.f, 0.f);
    for (int r = r0 + rsub; r < rend; r += 8) {
        float4 v = *(const float4*)&x[(size_t)r * D + f4];
        ps.x += v.x; ps.y += v.y; ps.z += v.z; ps.w += v.w;
        pq.x += v.x * v.x; pq.y += v.y * v.y; pq.z += v.z * v.z; pq.w += v.w * v.w;
    }
    atomicAdd(&ssum[f4 + 0], ps.x); atomicAdd(&ssum[f4 + 1], ps.y);
    atomicAdd(&ssum[f4 + 2], ps.z); atomicAdd(&ssum[f4 + 3], ps.w);
    atomicAdd(&ssq[f4 + 0], pq.x);  atomicAdd(&ssq[f4 + 1], pq.y);
    atomicAdd(&ssq[f4 + 2], pq.z);  atomicAdd(&ssq[f4 + 3], pq.w);
    __syncthreads();
    if (tid < D) {
        atomicAdd(&stats[tid], ssum[tid]);
        atomicAdd(&stats[D + tid], ssq[tid]);
    }
}

// writes bf16 h (row-major [node][D])
__global__ void standardize_kernel(const float* __restrict__ x, const float* __restrict__ stats,
                                   ushort* __restrict__ h) {
    const float invN = 1.f / (float)N_NODES;
    int stride = gridDim.x * blockDim.x;
    const int total = N_NODES * (D / 4);
    for (int idx = blockIdx.x * blockDim.x + threadIdx.x; idx < total; idx += stride) {
        int f = (idx & 31) * 4;
        float4 v = ((const float4*)x)[idx];
        float o[4];
        float vv[4] = {v.x, v.y, v.z, v.w};
#pragma unroll
        for (int j = 0; j < 4; ++j) {
            float mu = stats[f + j] * invN;
            float sd = sqrtf(stats[D + f + j] * invN - mu * mu);
            o[j] = (vv[j] - mu) / sd;
        }
        ((ushort4*)h)[idx] = make_ushort4(f2b(o[0]), f2b(o[1]), f2b(o[2]), f2b(o[3]));
    }
}

// ---------------- GIN aggregation (row-major h, fused BN affine + relu, 4-edge unroll) ---
__global__ void agg_kernel(const ushort* __restrict__ h, const int* __restrict__ rowptr,
                           const int* __restrict__ colidx, const float* __restrict__ eps, int l,
                           const float* __restrict__ ab, int relu_flag,
                           ushort* __restrict__ z0) {
    int node = blockIdx.x * 8 + (threadIdx.x >> 5);
    int f4 = (threadIdx.x & 31) * 4;
    const ushort* hp = h + f4;
    float A0 = ab[f4 + 0], A1 = ab[f4 + 1], A2 = ab[f4 + 2], A3 = ab[f4 + 3];
    float B0 = ab[D + f4 + 0], B1 = ab[D + f4 + 1], B2 = ab[D + f4 + 2], B3 = ab[D + f4 + 3];
    float lo = relu_flag ? 0.f : -INFINITY;
    auto R0 = [&](ushort u) { return fmaxf(fmaf(b2f(u), A0, B0), lo); };
    auto R1 = [&](ushort u) { return fmaxf(fmaf(b2f(u), A1, B1), lo); };
    auto R2 = [&](ushort u) { return fmaxf(fmaf(b2f(u), A2, B2), lo); };
    auto R3 = [&](ushort u) { return fmaxf(fmaf(b2f(u), A3, B3), lo); };

    ushort4 c = *(const ushort4*)&hp[(size_t)node * D];
    float se = 1.f + eps[l];
    float ax = se * R0(c.x), ay = se * R1(c.y), az = se * R2(c.z), aw = se * R3(c.w);

    int e = rowptr[node], e1 = rowptr[node + 1];
    for (; e + 4 <= e1; e += 4) {
        int s0 = colidx[e], s1 = colidx[e + 1], s2 = colidx[e + 2], s3 = colidx[e + 3];
        ushort4 v0 = *(const ushort4*)&hp[(size_t)s0 * D];
        ushort4 v1 = *(const ushort4*)&hp[(size_t)s1 * D];
        ushort4 v2 = *(const ushort4*)&hp[(size_t)s2 * D];
        ushort4 v3 = *(const ushort4*)&hp[(size_t)s3 * D];
        ax += (R0(v0.x) + R0(v1.x)) + (R0(v2.x) + R0(v3.x));
        ay += (R1(v0.y) + R1(v1.y)) + (R1(v2.y) + R1(v3.y));
        az += (R2(v0.z) + R2(v1.z)) + (R2(v2.z) + R2(v3.z));
        aw += (R3(v0.w) + R3(v1.w)) + (R3(v2.w) + R3(v3.w));
    }
    for (; e < e1; ++e) {
        ushort4 v0 = *(const ushort4*)&hp[(size_t)colidx[e] * D];
        ax += R0(v0.x); ay += R1(v0.y); az += R2(v0.z); aw += R3(v0.w);
    }
    *(ushort4*)&z0[(size_t)node * D + f4] = make_ushort4(f2b(ax), f2b(ay), f2b(az), f2b(aw));
}

// ---------------- weight prep: Wt[n][k] bf16 for both MLP weights, all layers ------------
__global__ void prep_wt_kernel(const float* __restrict__ W1, const float* __restrict__ W2,
                               ushort* __restrict__ wt) {
    int idx = blockIdx.x * blockDim.x + threadIdx.x;  // 131072 total
    int w = idx >> 16;
    int rem = idx & 65535;
    int l = rem >> 14;
    int nk = rem & 16383;
    int n = nk >> 7;
    int k = nk & 127;
    const float* W = w ? W2 : W1;
    wt[idx] = f2b(W[((size_t)(l * D + k)) * D + n]);
}

// ---------------- fused MFMA MLP, R10 rewrite ----------------
// Was: As+Bs LDS staging, 69KB LDS -> 2 blocks/CU, 6 barriers, MfmaUtil 3.4%,
// Occupancy 13% (latency-bound). Now: A and B fragments loaded DIRECTLY from
// global (A frag = contiguous 16B of row-major z0; B frag = 16B of 32KB
// L2-resident weights); z1 lives in wave-private LDS slice (no barrier
// between GEMM1/GEMM2); only the final block-wide store + stats need 2
// barriers. LDS 36KB -> 4 blocks/CU.
__launch_bounds__(256, 4)
__global__ void mlp_mfma_kernel(const ushort* __restrict__ z0,
                                const ushort* __restrict__ wt1, const float* __restrict__ b1,
                                const ushort* __restrict__ wt2, const float* __restrict__ b2,
                                ushort* __restrict__ out, float* __restrict__ stats) {
    __shared__ ushort Z[128 * LDK];   // 4 waves x private 32-row slice
    __shared__ float Ssum[D];
    __shared__ float Ssq[D];

    int tid = threadIdx.x;
    int lane = tid & 63;
    int wave = tid >> 6;
    int rb = blockIdx.x * 128;
    int lrow = lane & 15;
    int lk = lane >> 4;
    int klane = lk * 8;
    int wr0 = wave * 32;

    if (tid < D) { Ssum[tid] = 0.f; Ssq[tid] = 0.f; }

    bf16x8 zero8;
#pragma unroll
    for (int e = 0; e < 8; ++e) zero8[e] = 0;

    int ra0 = rb + wr0 + lrow;
    int ra1 = ra0 + 16;
    bool ok0 = ra0 < N_NODES;
    bool ok1 = ra1 < N_NODES;
    const ushort* pa0 = z0 + (size_t)ra0 * D + klane;
    const ushort* pa1 = z0 + (size_t)ra1 * D + klane;
    const ushort* pb1 = wt1 + (size_t)lrow * D + klane;   // + ct*16*D + ks*32
    const ushort* pb2 = wt2 + (size_t)lrow * D + klane;

    f32x4 acc[2][8];
#pragma unroll
    for (int a = 0; a < 2; ++a)
#pragma unroll
        for (int b = 0; b < 8; ++b)
#pragma unroll
            for (int r = 0; r < 4; ++r) acc[a][b][r] = 0.f;

    // ---- GEMM1: operands straight from global ----
#pragma unroll
    for (int ks = 0; ks < 4; ++ks) {
        bf16x8 a0 = ok0 ? *(const bf16x8*)(pa0 + ks * 32) : zero8;
        bf16x8 a1 = ok1 ? *(const bf16x8*)(pa1 + ks * 32) : zero8;
#pragma unroll
        for (int ct = 0; ct < 8; ++ct) {
            bf16x8 bb = *(const bf16x8*)(pb1 + (size_t)ct * 16 * D + ks * 32);
            acc[0][ct] = __builtin_amdgcn_mfma_f32_16x16x32_bf16(a0, bb, acc[0][ct], 0, 0, 0);
            acc[1][ct] = __builtin_amdgcn_mfma_f32_16x16x32_bf16(a1, bb, acc[1][ct], 0, 0, 0);
        }
    }

    // ---- z1 = relu(acc + b1) -> wave-private LDS slice (no barrier needed) ----
#pragma unroll
    for (int rt = 0; rt < 2; ++rt)
#pragma unroll
        for (int ct = 0; ct < 8; ++ct) {
            int col = ct * 16 + lrow;
            float bias = b1[col];
#pragma unroll
            for (int r = 0; r < 4; ++r) {
                int row = wr0 + rt * 16 + lk * 4 + r;
                Z[row * LDK + col] = f2b(fmaxf(acc[rt][ct][r] + bias, 0.f));
            }
        }

#pragma unroll
    for (int a = 0; a < 2; ++a)
#pragma unroll
        for (int b = 0; b < 8; ++b)
#pragma unroll
            for (int r = 0; r < 4; ++r) acc[a][b][r] = 0.f;

    // ---- GEMM2: A from own wave's z1 slice, B straight from global ----
#pragma unroll
    for (int ks = 0; ks < 4; ++ks) {
        int k0 = ks * 32 + klane;
        bf16x8 a0 = *(const bf16x8*)&Z[(wr0 + lrow) * LDK + k0];
        bf16x8 a1 = *(const bf16x8*)&Z[(wr0 + 16 + lrow) * LDK + k0];
#pragma unroll
        for (int ct = 0; ct < 8; ++ct) {
            bf16x8 bb = *(const bf16x8*)(pb2 + (size_t)ct * 16 * D + ks * 32);
            acc[0][ct] = __builtin_amdgcn_mfma_f32_16x16x32_bf16(a0, bb, acc[0][ct], 0, 0, 0);
            acc[1][ct] = __builtin_amdgcn_mfma_f32_16x16x32_bf16(a1, bb, acc[1][ct], 0, 0, 0);
        }
    }

    // ---- z2 epilogue: stage bf16 into own slice + per-lane stats ----
    float ls[8], lq[8];
#pragma unroll
    for (int ct = 0; ct < 8; ++ct) { ls[ct] = 0.f; lq[ct] = 0.f; }
#pragma unroll
    for (int rt = 0; rt < 2; ++rt)
#pragma unroll
        for (int ct = 0; ct < 8; ++ct) {
            int col = ct * 16 + lrow;
            float bias = b2[col];
#pragma unroll
            for (int r = 0; r < 4; ++r) {
                int row = wr0 + rt * 16 + lk * 4 + r;
                float v = fmaxf(acc[rt][ct][r] + bias, 0.f);
                Z[row * LDK + col] = f2b(v);
                if (rb + row < N_NODES) { ls[ct] += v; lq[ct] += v * v; }
            }
        }
    __syncthreads();   // z2 slices + Ssum/Ssq init visible block-wide

#pragma unroll
    for (int ct = 0; ct < 8; ++ct) {
        int col = ct * 16 + lrow;
        atomicAdd(&Ssum[col], ls[ct]);
        atomicAdd(&Ssq[col], lq[ct]);
    }

    // ---- block-wide coalesced store ----
#pragma unroll
    for (int i = 0; i < 8; ++i) {
        int c2 = tid + i * 256;
        int row = c2 >> 4;
        int cc = (c2 & 15) * 8;
        int gr = rb + row;
        if (gr < N_NODES)
            *(bf16x8*)&out[(size_t)gr * D + cc] = *(const bf16x8*)&Z[row * LDK + cc];
    }
    __syncthreads();   // stats atomics done
    if (tid < D) {
        atomicAdd(&stats[tid], Ssum[tid]);
        atomicAdd(&stats[D + tid], Ssq[tid]);
    }
}

// ---------------- BN prep: fold stats into per-feature affine A,B ----------------
__global__ void bnprep_kernel(const float* __restrict__ stats, const float* __restrict__ gamma,
                              const float* __restrict__ beta, float* __restrict__ ab) {
    int f = threadIdx.x;
    if (f < D) {
        const float invN = 1.f / (float)N_NODES;
        float mu = stats[f] * invN;
        float var = stats[D + f] * invN - mu * mu;
        float A = gamma[f] * rsqrtf(var + BN_EPS);
        ab[f] = A;
        ab[D + f] = beta[f] - mu * A;
    }
}

// ---------------- global_add_pool (batch sorted, row-major h) + fused final BN+relu ------
__global__ void pool_kernel(const ushort* __restrict__ h, const int* __restrict__ batch,
                            const float* __restrict__ ab, float* __restrict__ g) {
    int tid = threadIdx.x;
    int f4 = (tid & 31) * 4;
    int rsub = tid >> 5;
    int r0 = blockIdx.x * POOL_ROWS;
    int rend = r0 + POOL_ROWS;
    if (rend > N_NODES) rend = N_NODES;
    float A0 = ab[f4 + 0], A1 = ab[f4 + 1], A2 = ab[f4 + 2], A3 = ab[f4 + 3];
    float B0 = ab[D + f4 + 0], B1 = ab[D + f4 + 1], B2 = ab[D + f4 + 2], B3 = ab[D + f4 + 3];
    float4 acc = make_float4(0.f, 0.f, 0.f, 0.f);
    int cur = -1;
    for (int r = r0 + rsub; r < rend; r += 8) {
        int b = batch[r];
        if (b != cur) {
            if (cur >= 0) {
                atomicAdd(&g[cur * D + f4 + 0], acc.x);
                atomicAdd(&g[cur * D + f4 + 1], acc.y);
                atomicAdd(&g[cur * D + f4 + 2], acc.z);
                atomicAdd(&g[cur * D + f4 + 3], acc.w);
            }
            acc = make_float4(0.f, 0.f, 0.f, 0.f);
            cur = b;
        }
        ushort4 v = *(const ushort4*)&h[(size_t)r * D + f4];
        acc.x += fmaxf(fmaf(b2f(v.x), A0, B0), 0.f);
        acc.y += fmaxf(fmaf(b2f(v.y), A1, B1), 0.f);
        acc.z += fmaxf(fmaf(b2f(v.z), A2, B2), 0.f);
        acc.w += fmaxf(fmaf(b2f(v.w), A3, B3), 0.f);
    }
    if (cur >= 0) {
        atomicAdd(&g[cur * D + f4 + 0], acc.x);
        atomicAdd(&g[cur * D + f4 + 1], acc.y);
        atomicAdd(&g[cur * D + f4 + 2], acc.z);
        atomicAdd(&g[cur * D + f4 + 3], acc.w);
    }
}

// ---------------- MLP head: 64x128 -> 128 -> 64 -> 10 (fp32) ----------------
__launch_bounds__(512)
__global__ void head_kernel(const float* __restrict__ g,
                            const float* __restrict__ fcw1, const float* __restrict__ fcb1,
                            const float* __restrict__ fcw2, const float* __restrict__ fcb2,
                            const float* __restrict__ fcw3, const float* __restrict__ fcb3,
                            float* __restrict__ out) {
    __shared__ float G[64][128];
    __shared__ float T1[64][128];
    __shared__ float T2[64][64];
    int tid = threadIdx.x;
#pragma unroll
    for (int i = 0; i < 4; ++i) {
        int slot = tid + i * 512;
        ((float4*)G)[slot] = ((const float4*)g)[slot];
    }
    __syncthreads();
#pragma unroll 1
    for (int rep = 0; rep < 16; ++rep) {
        int o = tid + rep * 512;
        int r = o >> 7, c = o & 127;
        float acc = fcb1[c];
        for (int k = 0; k < 128; ++k) acc = fmaf(G[r][k], fcw1[k * 128 + c], acc);
        T1[r][c] = fmaxf(acc, 0.f);
    }
    __syncthreads();
#pragma unroll 1
    for (int rep = 0; rep < 8; ++rep) {
        int o = tid + rep * 512;
        int r = o >> 6, c = o & 63;
        float acc = fcb2[c];
        for (int k = 0; k < 128; ++k) acc = fmaf(T1[r][k], fcw2[k * 64 + c], acc);
        T2[r][c] = fmaxf(acc, 0.f);
    }
    __syncthreads();
    for (int o = tid; o < N_GRAPHS * N_CLASS; o += 512) {
        int r = o / 10, c = o % 10;
        float acc = fcb3[c];
        for (int k = 0; k < 64; ++k) acc = fmaf(T2[r][k], fcw3[k * 10 + c], acc);
        out[o] = acc;
    }
}

extern "C" void kernel_launch(void* const* d_in, const int* in_sizes, int n_in,
                              void* d_out, int out_size, void* d_ws, size_t ws_size,
                              hipStream_t stream) {
    const float* x        = (const float*)d_in[0];
    const int* edge_index = (const int*)d_in[1];
    const int* batch      = (const int*)d_in[2];
    const float* W1       = (const float*)d_in[3];
    const float* b1       = (const float*)d_in[4];
    const float* W2       = (const float*)d_in[5];
    const float* b2       = (const float*)d_in[6];
    const float* gamma    = (const float*)d_in[7];
    const float* beta     = (const float*)d_in[8];
    const float* eps      = (const float*)d_in[9];
    const float* fcw1     = (const float*)d_in[10];
    const float* fcb1     = (const float*)d_in[11];
    const float* fcw2     = (const float*)d_in[12];
    const float* fcb2     = (const float*)d_in[13];
    const float* fcw3     = (const float*)d_in[14];
    const float* fcb3     = (const float*)d_in[15];
    float* out = (float*)d_out;

    char* ws = (char*)d_ws;
    size_t off = 0;
    auto alloc = [&](size_t bytes) -> void* {
        void* p = ws + off;
        off = (off + bytes + 255) & ~(size_t)255;
        return p;
    };
    ushort* hbuf   = (ushort*)alloc((size_t)N_NODES * D * 2);           // 25.6 MB bf16
    ushort* z0buf  = (ushort*)alloc((size_t)N_NODES * D * 2);           // 25.6 MB bf16
    ushort* wtbuf  = (ushort*)alloc((size_t)2 * N_LAYERS * D * D * 2);  // 256 KB
    int2* bpairs   = (int2*)alloc((size_t)N_EDGES * 8);                 // 12.8 MB
    int* colidx    = (int*)alloc((size_t)N_EDGES * 4);                  // 6.4 MB
    int* rowptr    = (int*)alloc((size_t)(N_NODES + 1) * 4);
    int* bucketCount  = (int*)alloc((size_t)NB * 4);
    int* bucketBase   = (int*)alloc((size_t)(NB + 1) * 4);
    int* bucketCursor = (int*)alloc((size_t)NB * 4);
    float* statsAll = (float*)alloc(12 * D * 4);  // [l0 sum|sq][l1][l2][l3][scaler][abA|abB]
    float* gpool   = (float*)alloc((size_t)N_GRAPHS * D * 4);
    float* scalerStats = statsAll + 8 * D;
    float* ab          = statsAll + 10 * D;

    const int* srcArr = edge_index;
    const int* dstArr = edge_index + N_EDGES;

    // ---- one-shot prep (stats slabs, ab identity, gpool, bucketCount) ----
    prep_all_kernel<<<1, 1024, 0, stream>>>(statsAll, ab, gpool, bucketCount);

    // ---- bucketed CSR build ----
    bucket_count_kernel<<<EDGE_BLOCKS, 256, 0, stream>>>(dstArr, bucketCount);
    bucket_scan_kernel<<<1, 256, 0, stream>>>(bucketCount, bucketBase, bucketCursor);
    bucket_scatter_kernel<<<EDGE_BLOCKS, 256, 0, stream>>>(srcArr, dstArr, bucketCursor, bpairs);
    csr_build_kernel<<<NB, 512, 0, stream>>>(bpairs, bucketBase, rowptr, colidx);

    // ---- StandardScaler (h -> bf16) ----
    colstats_kernel<<<(N_NODES + 127) / 128, 256, 0, stream>>>(x, scalerStats);
    standardize_kernel<<<2048, 256, 0, stream>>>(x, scalerStats, hbuf);

    // ---- weight prep ----
    prep_wt_kernel<<<512, 256, 0, stream>>>(W1, W2, wtbuf);

    // ---- GIN layers (BN+relu of layer l fused into consumers of h_l) ----
    for (int l = 0; l < N_LAYERS; ++l) {
        float* lstats = statsAll + (size_t)l * 2 * D;
        agg_kernel<<<N_NODES / 8, 256, 0, stream>>>(hbuf, rowptr, colidx, eps, l,
                                                    ab, (l > 0) ? 1 : 0, z0buf);
        mlp_mfma_kernel<<<(N_NODES + 127) / 128, 256, 0, stream>>>(
            z0buf, wtbuf + (size_t)l * D * D, b1 + (size_t)l * D,
            wtbuf + (size_t)(N_LAYERS + l) * D * D, b2 + (size_t)l * D, hbuf, lstats);
        bnprep_kernel<<<1, 128, 0, stream>>>(lstats, gamma + (size_t)l * D,
                                             beta + (size_t)l * D, ab);
    }

    // ---- pool (fused final BN+relu) + head ----
    pool_kernel<<<(N_NODES + POOL_ROWS - 1) / POOL_ROWS, 256, 0, stream>>>(hbuf, batch, ab, gpool);
    head_kernel<<<1, 512, 0, stream>>>(gpool, fcw1, fcb1, fcw2, fcb2, fcw3, fcb3, out);
}